// Round 1
// baseline (2996.736 us; speedup 1.0000x reference)
//
#include <hip/hip_runtime.h>
#include <hip/hip_bf16.h>

#define DEVFN __device__ __forceinline__

// ---- workspace layout (bytes) ----
static constexpr size_t OFF_CTRS   = 0;                          // barrier arenas (zeroed)
static constexpr size_t OFF_FLAG   = 131072;                     // 4 B
static constexpr size_t OFF_STATS  = 131328;                     // 48 floats
static constexpr size_t OFF_EW     = 131584;                     // 4 floats
static constexpr size_t OFF_MASK32 = 131840;                     // 768 floats
static constexpr size_t OFF_EMB    = 135168;                     // 786,432 B
static constexpr size_t OFF_WPT    = 921600;                     // 8,388,608 B
static constexpr size_t OFF_BIAS   = 9310208;                    // 131,072 B
static constexpr size_t OFF_XW     = 9441280;                    // 50,331,648 B
static constexpr size_t OFF_OUT0   = 59772928;                   // 1,572,864 B
static constexpr size_t OFF_OUT1   = 61345792;                   // 1,572,864 B
static constexpr size_t OFF_Y      = 62918656;                   // 96*2*16384*4
static constexpr size_t OFF_H      = 75501568;                   // 97*2*2048*4

template<int BF>
DEVFN float ldin(const void* p, size_t i) {
  if (BF) {
    unsigned short u = ((const unsigned short*)p)[i];
    return __uint_as_float(((unsigned)u) << 16);
  }
  return ((const float*)p)[i];
}
DEVFN float ldraw(const void* p, size_t i, int bf) {
  if (bf) {
    unsigned short u = ((const unsigned short*)p)[i];
    return __uint_as_float(((unsigned)u) << 16);
  }
  return ((const float*)p)[i];
}

DEVFN float sigm(float x) { return 1.f / (1.f + __expf(-x)); }
DEVFN float clip3(float x) { return fminf(fmaxf(x, -3.f), 3.f); }

// ---------------- dtype detection ----------------
__global__ void detect_k(const unsigned* mask_raw, int* flagp) {
  if (threadIdx.x == 0) *flagp = (mask_raw[0] == 0x3F800000u) ? 0 : 1;
}

// ---------------- convert small tensors ----------------
template<int BF>
__global__ void convert_k(const int* flagp, const void* bias, const void* mask,
                          const void* ew, const void* gm,
                          float* bias32, float* mask32, float* ew32) {
  if (*flagp != BF) return;
  size_t i = (size_t)blockIdx.x * 256 + threadIdx.x;
  if (i >= 33540) return;
  if (i < 32768)       bias32[i] = ldin<BF>(bias, i);
  else if (i < 33536)  mask32[i - 32768] = ldin<BF>(mask, i - 32768);
  else if (i < 33539)  ew32[i - 33536]   = ldin<BF>(ew, i - 33536);
  else                 ew32[3] = ldin<BF>(gm, 0);
}

// ---------------- Wp transpose: Wp[dl][k][p] -> WpT[dl][p][k] ----------------
template<int BF>
__global__ void transpose_wp_k(const int* flagp, const void* Wp, float* WpT) {
  if (*flagp != BF) return;
  const int kt = blockIdx.x, pt = blockIdx.y, dl = blockIdx.z;
  __shared__ float tile[64][65];
  const int tid = threadIdx.x;
  for (int it = 0; it < 4; ++it) {
    int lin = it * 1024 + tid * 4;
    int kk = lin >> 6, pp = lin & 63;
    size_t src = ((size_t)(dl * 2048 + kt * 64 + kk)) * 256 + pt * 64 + pp;
    float v0, v1, v2, v3;
    if (BF) {
      const unsigned short* sp = (const unsigned short*)Wp + src;
      v0 = __uint_as_float(((unsigned)sp[0]) << 16);
      v1 = __uint_as_float(((unsigned)sp[1]) << 16);
      v2 = __uint_as_float(((unsigned)sp[2]) << 16);
      v3 = __uint_as_float(((unsigned)sp[3]) << 16);
    } else {
      float4 v = *(const float4*)((const float*)Wp + src);
      v0 = v.x; v1 = v.y; v2 = v.z; v3 = v.w;
    }
    tile[pp + 0][kk] = v0; tile[pp + 1][kk] = v1; tile[pp + 2][kk] = v2; tile[pp + 3][kk] = v3;
  }
  __syncthreads();
  for (int it = 0; it < 4; ++it) {
    int lin = it * 1024 + tid * 4;
    int pr = lin >> 6, kc = lin & 63;
    float4 o;
    o.x = tile[pr][kc + 0]; o.y = tile[pr][kc + 1]; o.z = tile[pr][kc + 2]; o.w = tile[pr][kc + 3];
    *(float4*)(WpT + ((size_t)(dl * 256 + pt * 64 + pr)) * 2048 + kt * 64 + kc) = o;
  }
}

// ---------------- embedding gather ----------------
template<int BF>
__global__ void gather_k(const int* flagp, const int* tokens, const void* et, float* emb) {
  if (*flagp != BF) return;
  const int bt = blockIdx.x;
  const int tok = tokens[bt];
  emb[(size_t)bt * 256 + threadIdx.x] = ldin<BF>(et, (size_t)tok * 256 + threadIdx.x);
}

// ---------------- xW = x @ Wk[dl] + b[dl] ----------------
template<int BF>
__global__ __launch_bounds__(256) void xw_gemm_k(
    const int* __restrict__ flagp, const float* __restrict__ x_fwd, const float* __restrict__ x_bwd,
    const void* __restrict__ Wk, const float* __restrict__ bias32, float* __restrict__ xW, int layer) {
  if (*flagp != BF) return;
  const int nt = blockIdx.x, mt = blockIdx.y, dir = blockIdx.z;
  const int dl = dir * 2 + layer;
  const float* xb = dir ? x_bwd : x_fwd;
  const int tid = threadIdx.x;

  __shared__ float As[16][68];
  __shared__ float Bs[16][68];

  float acc[4][4] = {};
  const int tx = tid & 15, ty = tid >> 4;

  const int am = tid >> 2;
  const int ak = (tid & 3) * 4;
  const int m_glob = mt * 64 + am;
  const int t_ = m_glob >> 3, b_ = m_glob & 7;
  const int tau = dir ? (95 - t_) : t_;
  const float* arow = xb + ((size_t)(b_ * 96 + tau)) * 256;

  const int bk = tid >> 4, bn = (tid & 15) * 4;

  for (int kb = 0; kb < 256; kb += 16) {
    float4 av = *(const float4*)(arow + kb + ak);
    As[ak + 0][am] = av.x; As[ak + 1][am] = av.y; As[ak + 2][am] = av.z; As[ak + 3][am] = av.w;

    size_t bidx = ((size_t)dl * 256 + (kb + bk)) * 8192 + (size_t)nt * 64 + bn;
    float b0, b1, b2, b3;
    if (BF) {
      ushort4 uv = *(const ushort4*)((const unsigned short*)Wk + bidx);
      b0 = __uint_as_float(((unsigned)uv.x) << 16);
      b1 = __uint_as_float(((unsigned)uv.y) << 16);
      b2 = __uint_as_float(((unsigned)uv.z) << 16);
      b3 = __uint_as_float(((unsigned)uv.w) << 16);
    } else {
      float4 fv = *(const float4*)((const float*)Wk + bidx);
      b0 = fv.x; b1 = fv.y; b2 = fv.z; b3 = fv.w;
    }
    Bs[bk][bn + 0] = b0; Bs[bk][bn + 1] = b1; Bs[bk][bn + 2] = b2; Bs[bk][bn + 3] = b3;
    __syncthreads();

#pragma unroll
    for (int kk = 0; kk < 16; ++kk) {
      float a0 = As[kk][ty * 4 + 0], a1 = As[kk][ty * 4 + 1], a2 = As[kk][ty * 4 + 2], a3 = As[kk][ty * 4 + 3];
      float c0 = Bs[kk][tx * 4 + 0], c1 = Bs[kk][tx * 4 + 1], c2 = Bs[kk][tx * 4 + 2], c3 = Bs[kk][tx * 4 + 3];
      acc[0][0] = fmaf(a0, c0, acc[0][0]); acc[0][1] = fmaf(a0, c1, acc[0][1]);
      acc[0][2] = fmaf(a0, c2, acc[0][2]); acc[0][3] = fmaf(a0, c3, acc[0][3]);
      acc[1][0] = fmaf(a1, c0, acc[1][0]); acc[1][1] = fmaf(a1, c1, acc[1][1]);
      acc[1][2] = fmaf(a1, c2, acc[1][2]); acc[1][3] = fmaf(a1, c3, acc[1][3]);
      acc[2][0] = fmaf(a2, c0, acc[2][0]); acc[2][1] = fmaf(a2, c1, acc[2][1]);
      acc[2][2] = fmaf(a2, c2, acc[2][2]); acc[2][3] = fmaf(a2, c3, acc[2][3]);
      acc[3][0] = fmaf(a3, c0, acc[3][0]); acc[3][1] = fmaf(a3, c1, acc[3][1]);
      acc[3][2] = fmaf(a3, c2, acc[3][2]); acc[3][3] = fmaf(a3, c3, acc[3][3]);
    }
    __syncthreads();
  }

  const int n0 = nt * 64 + tx * 4;
#pragma unroll
  for (int i = 0; i < 4; ++i) {
    int m = mt * 64 + ty * 4 + i;
    int tt = m >> 3, bb = m & 7;
    float4 o;
    o.x = acc[i][0] + bias32[dl * 8192 + n0 + 0];
    o.y = acc[i][1] + bias32[dl * 8192 + n0 + 1];
    o.z = acc[i][2] + bias32[dl * 8192 + n0 + 2];
    o.w = acc[i][3] + bias32[dl * 8192 + n0 + 3];
    *(float4*)(xW + (size_t)((dir * 96 + tt) * 8 + bb) * 8192 + n0) = o;
  }
}

// ---------------- relaxed two-level barrier, flattened broadcast ----------------
// Protocol (validated relaxed/agent scheme): cross-wg y/h data pushed with
// relaxed AGENT-scope atomic stores (bypass writer-XCD L2 to the coherence
// point); __syncthreads() before arrival drains vmcnt so those stores have
// completed; counters are relaxed MALL-point atomics; data readers use plain
// cached loads of per-step-unique addresses (never stale). NO acquire anywhere.
// Change vs prior round: gflag hop removed -- ALL wg leaders poll root
// directly (saves one full MALL round trip per barrier; 256 relaxed pollers
// on one MALL line is fine, loads don't serialize like RMWs).
DEVFN void wg_barrier(int* base, int g, int bcnt) {
  __syncthreads();
  if (threadIdx.x == 0) {
    int* gctr = base + (g >> 3) * 64;
    int* root = base + 32 * 64;
    int old = __hip_atomic_fetch_add(gctr, 1, __ATOMIC_RELAXED, __HIP_MEMORY_SCOPE_AGENT);
    if (old == 8 * bcnt - 1)
      __hip_atomic_fetch_add(root, 1, __ATOMIC_RELAXED, __HIP_MEMORY_SCOPE_AGENT);
    while (__hip_atomic_load(root, __ATOMIC_RELAXED, __HIP_MEMORY_SCOPE_AGENT) < 32 * bcnt)
      __builtin_amdgcn_s_sleep(1);
  }
  __syncthreads();
}

// ---------------- persistent LSTM scan ----------------
// Layouts (all changed this round for broadcast-optimal LDS access):
//   wr_s[k][col]   col = gate*8+cell (32 cols/wg)        -- read as float4, 8-lane b-broadcast
//   h_lds[p*8+b]   (hbuf transposed to match)            -- read as b32, 8-lane colq-broadcast
//   phase-1 map: ks=tid>>6 (wave), colq=(tid>>3)&7, b=tid&7
//   xW prefetched into a register at step top, staged via xw_s after matvec.
__global__ __launch_bounds__(256, 2) void scan_kernel(
    const float* __restrict__ xW, const void* __restrict__ WrRaw, const int* __restrict__ flagp,
    const float* __restrict__ WpT, const float* __restrict__ mask32,
    float* __restrict__ out, float* __restrict__ hbuf, float* __restrict__ ybuf,
    int* ctrs, int layer) {
  const int tid = threadIdx.x;
  const int w = blockIdx.x;
  const int dir = w >> 8;
  const int g = w & 255;
  const int dl = dir * 2 + layer;

  __shared__ __align__(16) float wr_s[256 * 32];   // 32 KB
  __shared__ __align__(16) float h_lds[2048];      // 8 KB
  __shared__ float4 wp4_s[512];                    // 8 KB
  __shared__ float4 zpart[288];                    // 4.5 KB (stride-9 pad)
  __shared__ float  z_s[32 * 9];                   // 1.1 KB (stride-9 pad)
  __shared__ __align__(16) float xw_s[256];        // 1 KB
  __shared__ float  mask_s[768];                   // 3 KB
  __shared__ float  c_s[64];
  __shared__ float  red_s[8];

  int* base = ctrs + (layer * 2 + dir) * 65 * 64;
  int bcnt = 0;
  const int bf = *flagp;

  // one-time loads
  {
    const size_t wrbase = (size_t)dl * 256 * 8192;
    for (int i = tid; i < 8192; i += 256) {
      int k = i >> 5, col = i & 31;
      wr_s[i] = ldraw(WrRaw, wrbase + (size_t)k * 8192 + (size_t)(col >> 3) * 2048 + g * 8 + (col & 7), bf);
    }
    const float4* wrow = (const float4*)(WpT + ((size_t)(dl * 256 + g)) * 2048);
    for (int i = tid; i < 512; i += 256) wp4_s[i] = wrow[i];
    for (int i = tid; i < 768; i += 256) mask_s[i] = mask32[i];
  }
  if (tid < 64) c_s[tid] = 0.f;

  const int ks = tid >> 6, colq = (tid >> 3) & 7, lb = tid & 7;
  const float4* wr4 = (const float4*)wr_s;
  const float4* xw4 = (const float4*)xw_s;

  for (int t = 0; t < 96; ++t) {
    const int tau = dir ? (95 - t) : t;
    const float* h_cur = hbuf + ((size_t)(t * 2 + dir)) * 2048;
    float* h_nxt = hbuf + ((size_t)((t + 1) * 2 + dir)) * 2048;
    float* y_t   = ybuf + ((size_t)(t * 2 + dir)) * 16384;

    // prefetch xW[t] for this wg (latency hidden under h-copy + matvec)
    float xwv;
    {
      int b = tid >> 5, col = tid & 31;
      xwv = xW[(size_t)((dir * 96 + t) * 8 + b) * 8192 + (col >> 3) * 2048 + g * 8 + (col & 7)];
    }

    // h copy into LDS, layout [p*8+b]
    if (t == 0) {
      ((float4*)h_lds)[tid * 2 + 0] = make_float4(0.f, 0.f, 0.f, 0.f);
      ((float4*)h_lds)[tid * 2 + 1] = make_float4(0.f, 0.f, 0.f, 0.f);
    } else {
      ((float4*)h_lds)[tid * 2 + 0] = ((const float4*)h_cur)[tid * 2 + 0];
      ((float4*)h_lds)[tid * 2 + 1] = ((const float4*)h_cur)[tid * 2 + 1];
    }
    __syncthreads();

    // ---- phase 1: z = xW[t] + h @ Wr ----
    // per wave: 8 distinct wr float4 (8-lane broadcast), 8 consecutive h words
    // (8-lane broadcast) -> conflict-free, 32 KB effective LDS read per step.
    {
      float4 acc = make_float4(0.f, 0.f, 0.f, 0.f);
#pragma unroll 16
      for (int i = 0; i < 64; ++i) {
        int k = (ks << 6) + i;
        float hv = h_lds[k * 8 + lb];
        float4 wv = wr4[k * 8 + colq];
        acc.x = fmaf(hv, wv.x, acc.x); acc.y = fmaf(hv, wv.y, acc.y);
        acc.z = fmaf(hv, wv.z, acc.z); acc.w = fmaf(hv, wv.w, acc.w);
      }
      zpart[(ks * 8 + colq) * 9 + lb] = acc;
      xw_s[tid] = xwv;
    }
    __syncthreads();

    if (tid < 64) {
      const int b3 = tid & 7, cq = tid >> 3;
      // 4-way k-split reduce + xW add
      float4 z0 = zpart[(0 * 8 + cq) * 9 + b3];
      float4 z1 = zpart[(1 * 8 + cq) * 9 + b3];
      float4 z2 = zpart[(2 * 8 + cq) * 9 + b3];
      float4 z3 = zpart[(3 * 8 + cq) * 9 + b3];
      float4 xv = xw4[b3 * 8 + cq];
      z_s[(cq * 4 + 0) * 9 + b3] = z0.x + z1.x + z2.x + z3.x + xv.x;
      z_s[(cq * 4 + 1) * 9 + b3] = z0.y + z1.y + z2.y + z3.y + xv.y;
      z_s[(cq * 4 + 2) * 9 + b3] = z0.z + z1.z + z2.z + z3.z + xv.z;
      z_s[(cq * 4 + 3) * 9 + b3] = z0.w + z1.w + z2.w + z3.w + xv.w;
      // gates -- same single wave as the stores above; ds ops are
      // compiler-ordered (lgkmcnt) within the wave, no barrier needed.
      const int cell = cq;  // cell index 0..7, batch b3
      float zi = z_s[(0  + cell) * 9 + b3];
      float zf = z_s[(8  + cell) * 9 + b3];
      float zg = z_s[(16 + cell) * 9 + b3];
      float zo = z_s[(24 + cell) * 9 + b3];
      float ig = sigm(zi), fg = sigm(zf), gg = tanhf(zg), og = sigm(zo);
      float cold = c_s[tid];
      float cc = clip3(fg * cold + ig * gg);
      float yv = og * tanhf(cc);
      float m = mask_s[b3 * 96 + tau];
      c_s[tid] = (m > 0.f) ? cc : cold;
      __hip_atomic_store(&y_t[b3 * 2048 + g * 8 + cell], yv, __ATOMIC_RELAXED, __HIP_MEMORY_SCOPE_AGENT);
    }
    wg_barrier(base, g, ++bcnt);

    // ---- phase 2: h[p=g] = clip(y @ Wp) ----
    {
      const int b = tid >> 5, kq = tid & 31;
      const float4* yb = (const float4*)y_t + b * 512;
      float s = 0.f;
#pragma unroll 4
      for (int i = 0; i < 16; ++i) {
        int k4 = i * 32 + kq;
        float4 yv = yb[k4];
        float4 wv = wp4_s[k4];
        s = fmaf(yv.x, wv.x, s); s = fmaf(yv.y, wv.y, s);
        s = fmaf(yv.z, wv.z, s); s = fmaf(yv.w, wv.w, s);
      }
      s += __shfl_down(s, 16, 32);
      s += __shfl_down(s, 8, 32);
      s += __shfl_down(s, 4, 32);
      s += __shfl_down(s, 2, 32);
      s += __shfl_down(s, 1, 32);
      if (kq == 0) red_s[b] = s;
    }
    __syncthreads();
    if (tid < 8) {
      float hc = clip3(red_s[tid]);
      float m = mask_s[tid * 96 + tau];
      float hp = h_lds[g * 8 + tid];           // h_t from LDS (no global re-read)
      float hv = (m > 0.f) ? hc : hp;
      __hip_atomic_store(&h_nxt[g * 8 + tid], hv, __ATOMIC_RELAXED, __HIP_MEMORY_SCOPE_AGENT);
      out[(size_t)((dir * 8 + tid) * 96 + tau) * 256 + g] = hv;
    }
    wg_barrier(base, g, ++bcnt);
  }
}

// ---------------- ELMo mix ----------------
DEVFN float layer_val(int l, int b, int t, int f, const float* emb, const float* out0, const float* out1) {
  const int half = f >> 8, p = f & 255;
  if (l == 0) return emb[(size_t)(b * 96 + t) * 256 + p];
  const size_t o = ((size_t)((half * 8 + b) * 96 + t)) * 256 + p;
  float v = out0[o];
  if (l == 2) v += out1[o];
  return v;
}

__global__ void mixA_k(const float* emb, const float* out0, const float* out1,
                       const float* mask32, float* stats) {
  const int b = blockIdx.x / 3, l = blockIdx.x % 3;
  float s1 = 0.f, s2 = 0.f;
  for (int idx = threadIdx.x; idx < 96 * 512; idx += 256) {
    int t = idx >> 9, f = idx & 511;
    float v = layer_val(l, b, t, f, emb, out0, out1);
    float m = mask32[b * 96 + t];
    s1 += m * v; s2 += m * v * v;
  }
  for (int off = 32; off; off >>= 1) { s1 += __shfl_down(s1, off); s2 += __shfl_down(s2, off); }
  __shared__ float p1[4], p2[4];
  if ((threadIdx.x & 63) == 0) { p1[threadIdx.x >> 6] = s1; p2[threadIdx.x >> 6] = s2; }
  __syncthreads();
  if (threadIdx.x == 0) {
    float S1 = p1[0] + p1[1] + p1[2] + p1[3];
    float S2 = p2[0] + p2[1] + p2[2] + p2[3];
    float num = 0.f;
    for (int t = 0; t < 96; ++t) num += mask32[b * 96 + t];
    float mean = S1 / num;
    float var = S2 / num - 2.f * mean * mean + 512.f * mean * mean;
    stats[(b * 3 + l) * 2 + 0] = mean;
    stats[(b * 3 + l) * 2 + 1] = rsqrtf(var + 1e-12f);
  }
}

__global__ void mixB_k(const int* flagp, const float* emb, const float* out0, const float* out1,
                       const float* stats, const float* ew32, void* outp) {
  const int idx = blockIdx.x * 256 + threadIdx.x;
  const int b = idx / 49152;
  const int r = idx % 49152;
  const int t = r >> 9, f = r & 511;
  float w0 = ew32[0], w1 = ew32[1], w2 = ew32[2], gm = ew32[3];
  float mx = fmaxf(w0, fmaxf(w1, w2));
  float e0 = __expf(w0 - mx), e1 = __expf(w1 - mx), e2 = __expf(w2 - mx);
  float inv = 1.f / (e0 + e1 + e2);
  float wl[3] = {e0 * inv, e1 * inv, e2 * inv};
  float acc = 0.f;
#pragma unroll
  for (int l = 0; l < 3; ++l) {
    float v = layer_val(l, b, t, f, emb, out0, out1);
    acc += wl[l] * (v - stats[(b * 3 + l) * 2]) * stats[(b * 3 + l) * 2 + 1];
  }
  acc *= gm;
  if (*flagp) ((__hip_bfloat16*)outp)[idx] = __float2bfloat16(acc);
  else        ((float*)outp)[idx] = acc;
}

// ---------------- host ----------------
extern "C" void kernel_launch(void* const* d_in, const int* in_sizes, int n_in,
                              void* d_out, int out_size, void* d_ws, size_t ws_size,
                              hipStream_t stream) {
  const int*  tokens = (const int*)d_in[0];
  const void* maskp  = d_in[1];
  const void* embt   = d_in[2];
  const void* Wk     = d_in[3];
  const void* WrRaw  = d_in[4];
  const void* bias   = d_in[5];
  const void* Wp     = d_in[6];
  const void* ew     = d_in[7];
  const void* gm     = d_in[8];

  char* ws = (char*)d_ws;
  int*   ctrs   = (int*)(ws + OFF_CTRS);
  int*   flagp  = (int*)(ws + OFF_FLAG);
  float* stats  = (float*)(ws + OFF_STATS);
  float* ew32   = (float*)(ws + OFF_EW);
  float* mask32 = (float*)(ws + OFF_MASK32);
  float* emb    = (float*)(ws + OFF_EMB);
  float* wpt    = (float*)(ws + OFF_WPT);
  float* bias32 = (float*)(ws + OFF_BIAS);
  float* xW     = (float*)(ws + OFF_XW);
  float* out0   = (float*)(ws + OFF_OUT0);
  float* out1   = (float*)(ws + OFF_OUT1);
  float* ybuf   = (float*)(ws + OFF_Y);
  float* hbuf   = (float*)(ws + OFF_H);

  hipMemsetAsync(d_ws, 0, 131072, stream);
  detect_k<<<1, 64, 0, stream>>>((const unsigned*)maskp, flagp);

  convert_k<0><<<132, 256, 0, stream>>>(flagp, bias, maskp, ew, gm, bias32, mask32, ew32);
  convert_k<1><<<132, 256, 0, stream>>>(flagp, bias, maskp, ew, gm, bias32, mask32, ew32);

  transpose_wp_k<0><<<dim3(32, 4, 4), 256, 0, stream>>>(flagp, Wp, wpt);
  transpose_wp_k<1><<<dim3(32, 4, 4), 256, 0, stream>>>(flagp, Wp, wpt);

  gather_k<0><<<768, 256, 0, stream>>>(flagp, tokens, embt, emb);
  gather_k<1><<<768, 256, 0, stream>>>(flagp, tokens, embt, emb);

  xw_gemm_k<0><<<dim3(128, 12, 2), 256, 0, stream>>>(flagp, emb, emb, Wk, bias32, xW, 0);
  xw_gemm_k<1><<<dim3(128, 12, 2), 256, 0, stream>>>(flagp, emb, emb, Wk, bias32, xW, 0);

  int l0 = 0, l1 = 1;
  {
    void* args[] = {&xW, &WrRaw, &flagp, &wpt, &mask32, &out0, &hbuf, &ybuf, &ctrs, &l0};
    hipError_t e = hipLaunchCooperativeKernel((void*)scan_kernel, dim3(512), dim3(256), args, 0, stream);
    if (e != hipSuccess)
      scan_kernel<<<512, 256, 0, stream>>>(xW, WrRaw, flagp, wpt, mask32, out0, hbuf, ybuf, ctrs, 0);
  }

  float* x_fwd = out0;
  float* x_bwd = out0 + (size_t)8 * 96 * 256;
  xw_gemm_k<0><<<dim3(128, 12, 2), 256, 0, stream>>>(flagp, x_fwd, x_bwd, Wk, bias32, xW, 1);
  xw_gemm_k<1><<<dim3(128, 12, 2), 256, 0, stream>>>(flagp, x_fwd, x_bwd, Wk, bias32, xW, 1);

  {
    void* args[] = {&xW, &WrRaw, &flagp, &wpt, &mask32, &out1, &hbuf, &ybuf, &ctrs, &l1};
    hipError_t e = hipLaunchCooperativeKernel((void*)scan_kernel, dim3(512), dim3(256), args, 0, stream);
    if (e != hipSuccess)
      scan_kernel<<<512, 256, 0, stream>>>(xW, WrRaw, flagp, wpt, mask32, out1, hbuf, ybuf, ctrs, 1);
  }

  mixA_k<<<24, 256, 0, stream>>>(emb, out0, out1, mask32, stats);
  mixB_k<<<1536, 256, 0, stream>>>(flagp, emb, out0, out1, stats, ew32, d_out);
}

// Round 2
// 2416.460 us; speedup vs baseline: 1.2401x; 1.2401x over previous
//
#include <hip/hip_runtime.h>
#include <hip/hip_bf16.h>

#define DEVFN __device__ __forceinline__

// ---- workspace layout (bytes) ----
static constexpr size_t OFF_CTRS   = 0;                          // barrier arenas (zeroed)
static constexpr size_t OFF_FLAG   = 131072;                     // 4 B
static constexpr size_t OFF_STATS  = 131328;                     // 48 floats
static constexpr size_t OFF_EW     = 131584;                     // 4 floats
static constexpr size_t OFF_MASK32 = 131840;                     // 768 floats
static constexpr size_t OFF_EMB    = 135168;                     // 786,432 B
static constexpr size_t OFF_WPT    = 921600;                     // 8,388,608 B
static constexpr size_t OFF_BIAS   = 9310208;                    // 131,072 B
static constexpr size_t OFF_XW     = 9441280;                    // 50,331,648 B
static constexpr size_t OFF_OUT0   = 59772928;                   // 1,572,864 B
static constexpr size_t OFF_OUT1   = 61345792;                   // 1,572,864 B
static constexpr size_t OFF_Y      = 62918656;                   // 96*2*16384*4
static constexpr size_t OFF_H      = 75501568;                   // 97*2*2048*4

template<int BF>
DEVFN float ldin(const void* p, size_t i) {
  if (BF) {
    unsigned short u = ((const unsigned short*)p)[i];
    return __uint_as_float(((unsigned)u) << 16);
  }
  return ((const float*)p)[i];
}
DEVFN float ldraw(const void* p, size_t i, int bf) {
  if (bf) {
    unsigned short u = ((const unsigned short*)p)[i];
    return __uint_as_float(((unsigned)u) << 16);
  }
  return ((const float*)p)[i];
}

DEVFN float sigm(float x) { return 1.f / (1.f + __expf(-x)); }
DEVFN float clip3(float x) { return fminf(fmaxf(x, -3.f), 3.f); }

// ---------------- dtype detection ----------------
__global__ void detect_k(const unsigned* mask_raw, int* flagp) {
  if (threadIdx.x == 0) *flagp = (mask_raw[0] == 0x3F800000u) ? 0 : 1;
}

// ---------------- convert small tensors ----------------
template<int BF>
__global__ void convert_k(const int* flagp, const void* bias, const void* mask,
                          const void* ew, const void* gm,
                          float* bias32, float* mask32, float* ew32) {
  if (*flagp != BF) return;
  size_t i = (size_t)blockIdx.x * 256 + threadIdx.x;
  if (i >= 33540) return;
  if (i < 32768)       bias32[i] = ldin<BF>(bias, i);
  else if (i < 33536)  mask32[i - 32768] = ldin<BF>(mask, i - 32768);
  else if (i < 33539)  ew32[i - 33536]   = ldin<BF>(ew, i - 33536);
  else                 ew32[3] = ldin<BF>(gm, 0);
}

// ---------------- Wp transpose: Wp[dl][k][p] -> WpT[dl][p][k] ----------------
template<int BF>
__global__ void transpose_wp_k(const int* flagp, const void* Wp, float* WpT) {
  if (*flagp != BF) return;
  const int kt = blockIdx.x, pt = blockIdx.y, dl = blockIdx.z;
  __shared__ float tile[64][65];
  const int tid = threadIdx.x;
  for (int it = 0; it < 4; ++it) {
    int lin = it * 1024 + tid * 4;
    int kk = lin >> 6, pp = lin & 63;
    size_t src = ((size_t)(dl * 2048 + kt * 64 + kk)) * 256 + pt * 64 + pp;
    float v0, v1, v2, v3;
    if (BF) {
      const unsigned short* sp = (const unsigned short*)Wp + src;
      v0 = __uint_as_float(((unsigned)sp[0]) << 16);
      v1 = __uint_as_float(((unsigned)sp[1]) << 16);
      v2 = __uint_as_float(((unsigned)sp[2]) << 16);
      v3 = __uint_as_float(((unsigned)sp[3]) << 16);
    } else {
      float4 v = *(const float4*)((const float*)Wp + src);
      v0 = v.x; v1 = v.y; v2 = v.z; v3 = v.w;
    }
    tile[pp + 0][kk] = v0; tile[pp + 1][kk] = v1; tile[pp + 2][kk] = v2; tile[pp + 3][kk] = v3;
  }
  __syncthreads();
  for (int it = 0; it < 4; ++it) {
    int lin = it * 1024 + tid * 4;
    int pr = lin >> 6, kc = lin & 63;
    float4 o;
    o.x = tile[pr][kc + 0]; o.y = tile[pr][kc + 1]; o.z = tile[pr][kc + 2]; o.w = tile[pr][kc + 3];
    *(float4*)(WpT + ((size_t)(dl * 256 + pt * 64 + pr)) * 2048 + kt * 64 + kc) = o;
  }
}

// ---------------- embedding gather ----------------
template<int BF>
__global__ void gather_k(const int* flagp, const int* tokens, const void* et, float* emb) {
  if (*flagp != BF) return;
  const int bt = blockIdx.x;
  const int tok = tokens[bt];
  emb[(size_t)bt * 256 + threadIdx.x] = ldin<BF>(et, (size_t)tok * 256 + threadIdx.x);
}

// ---------------- xW = x @ Wk[dl] + b[dl] ----------------
template<int BF>
__global__ __launch_bounds__(256) void xw_gemm_k(
    const int* __restrict__ flagp, const float* __restrict__ x_fwd, const float* __restrict__ x_bwd,
    const void* __restrict__ Wk, const float* __restrict__ bias32, float* __restrict__ xW, int layer) {
  if (*flagp != BF) return;
  const int nt = blockIdx.x, mt = blockIdx.y, dir = blockIdx.z;
  const int dl = dir * 2 + layer;
  const float* xb = dir ? x_bwd : x_fwd;
  const int tid = threadIdx.x;

  __shared__ float As[16][68];
  __shared__ float Bs[16][68];

  float acc[4][4] = {};
  const int tx = tid & 15, ty = tid >> 4;

  const int am = tid >> 2;
  const int ak = (tid & 3) * 4;
  const int m_glob = mt * 64 + am;
  const int t_ = m_glob >> 3, b_ = m_glob & 7;
  const int tau = dir ? (95 - t_) : t_;
  const float* arow = xb + ((size_t)(b_ * 96 + tau)) * 256;

  const int bk = tid >> 4, bn = (tid & 15) * 4;

  for (int kb = 0; kb < 256; kb += 16) {
    float4 av = *(const float4*)(arow + kb + ak);
    As[ak + 0][am] = av.x; As[ak + 1][am] = av.y; As[ak + 2][am] = av.z; As[ak + 3][am] = av.w;

    size_t bidx = ((size_t)dl * 256 + (kb + bk)) * 8192 + (size_t)nt * 64 + bn;
    float b0, b1, b2, b3;
    if (BF) {
      ushort4 uv = *(const ushort4*)((const unsigned short*)Wk + bidx);
      b0 = __uint_as_float(((unsigned)uv.x) << 16);
      b1 = __uint_as_float(((unsigned)uv.y) << 16);
      b2 = __uint_as_float(((unsigned)uv.z) << 16);
      b3 = __uint_as_float(((unsigned)uv.w) << 16);
    } else {
      float4 fv = *(const float4*)((const float*)Wk + bidx);
      b0 = fv.x; b1 = fv.y; b2 = fv.z; b3 = fv.w;
    }
    Bs[bk][bn + 0] = b0; Bs[bk][bn + 1] = b1; Bs[bk][bn + 2] = b2; Bs[bk][bn + 3] = b3;
    __syncthreads();

#pragma unroll
    for (int kk = 0; kk < 16; ++kk) {
      float a0 = As[kk][ty * 4 + 0], a1 = As[kk][ty * 4 + 1], a2 = As[kk][ty * 4 + 2], a3 = As[kk][ty * 4 + 3];
      float c0 = Bs[kk][tx * 4 + 0], c1 = Bs[kk][tx * 4 + 1], c2 = Bs[kk][tx * 4 + 2], c3 = Bs[kk][tx * 4 + 3];
      acc[0][0] = fmaf(a0, c0, acc[0][0]); acc[0][1] = fmaf(a0, c1, acc[0][1]);
      acc[0][2] = fmaf(a0, c2, acc[0][2]); acc[0][3] = fmaf(a0, c3, acc[0][3]);
      acc[1][0] = fmaf(a1, c0, acc[1][0]); acc[1][1] = fmaf(a1, c1, acc[1][1]);
      acc[1][2] = fmaf(a1, c2, acc[1][2]); acc[1][3] = fmaf(a1, c3, acc[1][3]);
      acc[2][0] = fmaf(a2, c0, acc[2][0]); acc[2][1] = fmaf(a2, c1, acc[2][1]);
      acc[2][2] = fmaf(a2, c2, acc[2][2]); acc[2][3] = fmaf(a2, c3, acc[2][3]);
      acc[3][0] = fmaf(a3, c0, acc[3][0]); acc[3][1] = fmaf(a3, c1, acc[3][1]);
      acc[3][2] = fmaf(a3, c2, acc[3][2]); acc[3][3] = fmaf(a3, c3, acc[3][3]);
    }
    __syncthreads();
  }

  const int n0 = nt * 64 + tx * 4;
#pragma unroll
  for (int i = 0; i < 4; ++i) {
    int m = mt * 64 + ty * 4 + i;
    int tt = m >> 3, bb = m & 7;
    float4 o;
    o.x = acc[i][0] + bias32[dl * 8192 + n0 + 0];
    o.y = acc[i][1] + bias32[dl * 8192 + n0 + 1];
    o.z = acc[i][2] + bias32[dl * 8192 + n0 + 2];
    o.w = acc[i][3] + bias32[dl * 8192 + n0 + 3];
    *(float4*)(xW + (size_t)((dir * 96 + tt) * 8 + bb) * 8192 + n0) = o;
  }
}

// ---------------- flat-detection barrier ----------------
// Theory (round-2): the nested barrier is a 4-5 hop serial MALL chain
// (arrive RMW -> root RMW -> root poll -> gflag store -> gflag poll) ~5us.
// Flat detection: arrivals spread over 64 lines (4 wgs/line, RMW depth 4);
// completion detected by wave 0's 64 lanes loading all 64 lines in ONE
// vector atomic-load + __all. Chain: drain -> arrival visible -> poll catch
// ~1.5-2us. Contention per line: 256 pollers but only 4 RMWs (round-1's
// flat-root failure was 256 pollers + 32 RMWs on ONE line).
// Memory protocol unchanged (validated): relaxed AGENT atomic data stores to
// MALL, vmcnt(0) drain before arrival, atomic relaxed counter ops, plain
// cached loads only of per-step-unique data addresses.

// ---------------- persistent LSTM scan ----------------
__global__ __launch_bounds__(256, 2) void scan_kernel(
    const float* __restrict__ xW, const void* __restrict__ WrRaw, const int* __restrict__ flagp,
    const float* __restrict__ WpT, const float* __restrict__ mask32,
    float* __restrict__ out, float* __restrict__ hbuf, float* __restrict__ ybuf,
    int* ctrs, int layer) {
  const int tid = threadIdx.x;
  const int w = blockIdx.x;
  const int dir = w >> 8;
  const int g = w & 255;
  const int dl = dir * 2 + layer;

  __shared__ __align__(16) float wr_s[256 * 32];   // 32 KB
  __shared__ __align__(16) float h_lds[2048];      // 8 KB
  __shared__ float4 wp4_s[512];                    // 8 KB
  __shared__ float4 zpart[288];                    // 4.5 KB (stride-9 pad)
  __shared__ float  z_s[32 * 9];                   // 1.1 KB (stride-9 pad)
  __shared__ __align__(16) float xw_s[256];        // 1 KB
  __shared__ float  mask_s[768];                   // 3 KB
  __shared__ float  c_s[64];
  __shared__ float  red_s[8];

  int* base = ctrs + (layer * 2 + dir) * 65 * 64;  // 64 lines x 64 ints used
  int* aline = base + (g >> 2) * 64;               // my arrival line (4 wgs each)
  int ep = 0;
  const int bf = *flagp;

  // one-time loads
  {
    const size_t wrbase = (size_t)dl * 256 * 8192;
    for (int i = tid; i < 8192; i += 256) {
      int k = i >> 5, col = i & 31;
      wr_s[i] = ldraw(WrRaw, wrbase + (size_t)k * 8192 + (size_t)(col >> 3) * 2048 + g * 8 + (col & 7), bf);
    }
    const float4* wrow = (const float4*)(WpT + ((size_t)(dl * 256 + g)) * 2048);
    for (int i = tid; i < 512; i += 256) wp4_s[i] = wrow[i];
    for (int i = tid; i < 768; i += 256) mask_s[i] = mask32[i];
  }
  if (tid < 64) c_s[tid] = 0.f;

  const int ks = tid >> 6, colq = (tid >> 3) & 7, lb = tid & 7;
  const float4* wr4 = (const float4*)wr_s;
  const float4* xw4 = (const float4*)xw_s;
  int* myline = base + (tid & 63) * 64;            // poll line for wave-0 lanes

  for (int t = 0; t < 96; ++t) {
    const int tau = dir ? (95 - t) : t;
    const float* h_cur = hbuf + ((size_t)(t * 2 + dir)) * 2048;
    float* h_nxt = hbuf + ((size_t)((t + 1) * 2 + dir)) * 2048;
    float* y_t   = ybuf + ((size_t)(t * 2 + dir)) * 16384;

    // prefetch xW[t] for this wg (latency hidden under h-copy + matvec)
    float xwv;
    {
      int b = tid >> 5, col = tid & 31;
      xwv = xW[(size_t)((dir * 96 + t) * 8 + b) * 8192 + (col >> 3) * 2048 + g * 8 + (col & 7)];
    }

    // h copy into LDS, layout [p*8+b]
    if (t == 0) {
      ((float4*)h_lds)[tid * 2 + 0] = make_float4(0.f, 0.f, 0.f, 0.f);
      ((float4*)h_lds)[tid * 2 + 1] = make_float4(0.f, 0.f, 0.f, 0.f);
    } else {
      ((float4*)h_lds)[tid * 2 + 0] = ((const float4*)h_cur)[tid * 2 + 0];
      ((float4*)h_lds)[tid * 2 + 1] = ((const float4*)h_cur)[tid * 2 + 1];
    }
    __syncthreads();

    // ---- phase 1: z = xW[t] + h @ Wr ----
    {
      float4 acc = make_float4(0.f, 0.f, 0.f, 0.f);
#pragma unroll 16
      for (int i = 0; i < 64; ++i) {
        int k = (ks << 6) + i;
        float hv = h_lds[k * 8 + lb];
        float4 wv = wr4[k * 8 + colq];
        acc.x = fmaf(hv, wv.x, acc.x); acc.y = fmaf(hv, wv.y, acc.y);
        acc.z = fmaf(hv, wv.z, acc.z); acc.w = fmaf(hv, wv.w, acc.w);
      }
      zpart[(ks * 8 + colq) * 9 + lb] = acc;
      xw_s[tid] = xwv;
    }
    __syncthreads();

    ++ep;  // epoch for barrier A (value after all arrivals: 4*ep per line)
    if (tid < 64) {
      {
        const int b3 = tid & 7, cq = tid >> 3;
        float4 z0 = zpart[(0 * 8 + cq) * 9 + b3];
        float4 z1 = zpart[(1 * 8 + cq) * 9 + b3];
        float4 z2 = zpart[(2 * 8 + cq) * 9 + b3];
        float4 z3 = zpart[(3 * 8 + cq) * 9 + b3];
        float4 xv = xw4[b3 * 8 + cq];
        z_s[(cq * 4 + 0) * 9 + b3] = z0.x + z1.x + z2.x + z3.x + xv.x;
        z_s[(cq * 4 + 1) * 9 + b3] = z0.y + z1.y + z2.y + z3.y + xv.y;
        z_s[(cq * 4 + 2) * 9 + b3] = z0.z + z1.z + z2.z + z3.z + xv.z;
        z_s[(cq * 4 + 3) * 9 + b3] = z0.w + z1.w + z2.w + z3.w + xv.w;
        const int cell = cq;
        float zi = z_s[(0  + cell) * 9 + b3];
        float zf = z_s[(8  + cell) * 9 + b3];
        float zg = z_s[(16 + cell) * 9 + b3];
        float zo = z_s[(24 + cell) * 9 + b3];
        float ig = sigm(zi), fg = sigm(zf), gg = tanhf(zg), og = sigm(zo);
        float cold = c_s[tid];
        float cc = clip3(fg * cold + ig * gg);
        float yv = og * tanhf(cc);
        float m = mask_s[b3 * 96 + tau];
        c_s[tid] = (m > 0.f) ? cc : cold;
        __hip_atomic_store(&y_t[b3 * 2048 + g * 8 + cell], yv, __ATOMIC_RELAXED, __HIP_MEMORY_SCOPE_AGENT);
      }
      // drain y stores, arrive, flat-poll all 64 lines
      asm volatile("s_waitcnt vmcnt(0)" ::: "memory");
      if (tid == 0)
        __hip_atomic_fetch_add(aline, 1, __ATOMIC_RELAXED, __HIP_MEMORY_SCOPE_AGENT);
      const int tgt = 4 * ep;
      int v = __hip_atomic_load(myline, __ATOMIC_RELAXED, __HIP_MEMORY_SCOPE_AGENT);
      while (!__all(v >= tgt)) {
        __builtin_amdgcn_s_sleep(1);
        v = __hip_atomic_load(myline, __ATOMIC_RELAXED, __HIP_MEMORY_SCOPE_AGENT);
      }
    }
    __syncthreads();

    // ---- phase 2: h[p=g] = clip(y @ Wp) ----
    {
      const int b = tid >> 5, kq = tid & 31;
      const float4* yb = (const float4*)y_t + b * 512;
      float s = 0.f;
#pragma unroll 8
      for (int i = 0; i < 16; ++i) {
        int k4 = i * 32 + kq;
        float4 yv = yb[k4];
        float4 wv = wp4_s[k4];
        s = fmaf(yv.x, wv.x, s); s = fmaf(yv.y, wv.y, s);
        s = fmaf(yv.z, wv.z, s); s = fmaf(yv.w, wv.w, s);
      }
      s += __shfl_down(s, 16, 32);
      s += __shfl_down(s, 8, 32);
      s += __shfl_down(s, 4, 32);
      s += __shfl_down(s, 2, 32);
      s += __shfl_down(s, 1, 32);
      if (kq == 0) red_s[b] = s;
    }
    __syncthreads();

    ++ep;  // epoch for barrier B
    if (tid < 64) {
      if (tid < 8) {
        float hc = clip3(red_s[tid]);
        float m = mask_s[tid * 96 + tau];
        float hp = h_lds[g * 8 + tid];         // h_t from LDS (no global re-read)
        float hv = (m > 0.f) ? hc : hp;
        __hip_atomic_store(&h_nxt[g * 8 + tid], hv, __ATOMIC_RELAXED, __HIP_MEMORY_SCOPE_AGENT);
        out[(size_t)((dir * 8 + tid) * 96 + tau) * 256 + g] = hv;
      }
      asm volatile("s_waitcnt vmcnt(0)" ::: "memory");
      if (tid == 0)
        __hip_atomic_fetch_add(aline, 1, __ATOMIC_RELAXED, __HIP_MEMORY_SCOPE_AGENT);
      const int tgt = 4 * ep;
      int v = __hip_atomic_load(myline, __ATOMIC_RELAXED, __HIP_MEMORY_SCOPE_AGENT);
      while (!__all(v >= tgt)) {
        __builtin_amdgcn_s_sleep(1);
        v = __hip_atomic_load(myline, __ATOMIC_RELAXED, __HIP_MEMORY_SCOPE_AGENT);
      }
    }
    __syncthreads();
  }
}

// ---------------- ELMo mix ----------------
DEVFN float layer_val(int l, int b, int t, int f, const float* emb, const float* out0, const float* out1) {
  const int half = f >> 8, p = f & 255;
  if (l == 0) return emb[(size_t)(b * 96 + t) * 256 + p];
  const size_t o = ((size_t)((half * 8 + b) * 96 + t)) * 256 + p;
  float v = out0[o];
  if (l == 2) v += out1[o];
  return v;
}

__global__ void mixA_k(const float* emb, const float* out0, const float* out1,
                       const float* mask32, float* stats) {
  const int b = blockIdx.x / 3, l = blockIdx.x % 3;
  float s1 = 0.f, s2 = 0.f;
  for (int idx = threadIdx.x; idx < 96 * 512; idx += 256) {
    int t = idx >> 9, f = idx & 511;
    float v = layer_val(l, b, t, f, emb, out0, out1);
    float m = mask32[b * 96 + t];
    s1 += m * v; s2 += m * v * v;
  }
  for (int off = 32; off; off >>= 1) { s1 += __shfl_down(s1, off); s2 += __shfl_down(s2, off); }
  __shared__ float p1[4], p2[4];
  if ((threadIdx.x & 63) == 0) { p1[threadIdx.x >> 6] = s1; p2[threadIdx.x >> 6] = s2; }
  __syncthreads();
  if (threadIdx.x == 0) {
    float S1 = p1[0] + p1[1] + p1[2] + p1[3];
    float S2 = p2[0] + p2[1] + p2[2] + p2[3];
    float num = 0.f;
    for (int t = 0; t < 96; ++t) num += mask32[b * 96 + t];
    float mean = S1 / num;
    float var = S2 / num - 2.f * mean * mean + 512.f * mean * mean;
    stats[(b * 3 + l) * 2 + 0] = mean;
    stats[(b * 3 + l) * 2 + 1] = rsqrtf(var + 1e-12f);
  }
}

__global__ void mixB_k(const int* flagp, const float* emb, const float* out0, const float* out1,
                       const float* stats, const float* ew32, void* outp) {
  const int idx = blockIdx.x * 256 + threadIdx.x;
  const int b = idx / 49152;
  const int r = idx % 49152;
  const int t = r >> 9, f = r & 511;
  float w0 = ew32[0], w1 = ew32[1], w2 = ew32[2], gm = ew32[3];
  float mx = fmaxf(w0, fmaxf(w1, w2));
  float e0 = __expf(w0 - mx), e1 = __expf(w1 - mx), e2 = __expf(w2 - mx);
  float inv = 1.f / (e0 + e1 + e2);
  float wl[3] = {e0 * inv, e1 * inv, e2 * inv};
  float acc = 0.f;
#pragma unroll
  for (int l = 0; l < 3; ++l) {
    float v = layer_val(l, b, t, f, emb, out0, out1);
    acc += wl[l] * (v - stats[(b * 3 + l) * 2]) * stats[(b * 3 + l) * 2 + 1];
  }
  acc *= gm;
  if (*flagp) ((__hip_bfloat16*)outp)[idx] = __float2bfloat16(acc);
  else        ((float*)outp)[idx] = acc;
}

// ---------------- host ----------------
extern "C" void kernel_launch(void* const* d_in, const int* in_sizes, int n_in,
                              void* d_out, int out_size, void* d_ws, size_t ws_size,
                              hipStream_t stream) {
  const int*  tokens = (const int*)d_in[0];
  const void* maskp  = d_in[1];
  const void* embt   = d_in[2];
  const void* Wk     = d_in[3];
  const void* WrRaw  = d_in[4];
  const void* bias   = d_in[5];
  const void* Wp     = d_in[6];
  const void* ew     = d_in[7];
  const void* gm     = d_in[8];

  char* ws = (char*)d_ws;
  int*   ctrs   = (int*)(ws + OFF_CTRS);
  int*   flagp  = (int*)(ws + OFF_FLAG);
  float* stats  = (float*)(ws + OFF_STATS);
  float* ew32   = (float*)(ws + OFF_EW);
  float* mask32 = (float*)(ws + OFF_MASK32);
  float* emb    = (float*)(ws + OFF_EMB);
  float* wpt    = (float*)(ws + OFF_WPT);
  float* bias32 = (float*)(ws + OFF_BIAS);
  float* xW     = (float*)(ws + OFF_XW);
  float* out0   = (float*)(ws + OFF_OUT0);
  float* out1   = (float*)(ws + OFF_OUT1);
  float* ybuf   = (float*)(ws + OFF_Y);
  float* hbuf   = (float*)(ws + OFF_H);

  hipMemsetAsync(d_ws, 0, 131072, stream);
  detect_k<<<1, 64, 0, stream>>>((const unsigned*)maskp, flagp);

  convert_k<0><<<132, 256, 0, stream>>>(flagp, bias, maskp, ew, gm, bias32, mask32, ew32);
  convert_k<1><<<132, 256, 0, stream>>>(flagp, bias, maskp, ew, gm, bias32, mask32, ew32);

  transpose_wp_k<0><<<dim3(32, 4, 4), 256, 0, stream>>>(flagp, Wp, wpt);
  transpose_wp_k<1><<<dim3(32, 4, 4), 256, 0, stream>>>(flagp, Wp, wpt);

  gather_k<0><<<768, 256, 0, stream>>>(flagp, tokens, embt, emb);
  gather_k<1><<<768, 256, 0, stream>>>(flagp, tokens, embt, emb);

  xw_gemm_k<0><<<dim3(128, 12, 2), 256, 0, stream>>>(flagp, emb, emb, Wk, bias32, xW, 0);
  xw_gemm_k<1><<<dim3(128, 12, 2), 256, 0, stream>>>(flagp, emb, emb, Wk, bias32, xW, 0);

  int l0 = 0, l1 = 1;
  {
    void* args[] = {&xW, &WrRaw, &flagp, &wpt, &mask32, &out0, &hbuf, &ybuf, &ctrs, &l0};
    hipError_t e = hipLaunchCooperativeKernel((void*)scan_kernel, dim3(512), dim3(256), args, 0, stream);
    if (e != hipSuccess)
      scan_kernel<<<512, 256, 0, stream>>>(xW, WrRaw, flagp, wpt, mask32, out0, hbuf, ybuf, ctrs, 0);
  }

  float* x_fwd = out0;
  float* x_bwd = out0 + (size_t)8 * 96 * 256;
  xw_gemm_k<0><<<dim3(128, 12, 2), 256, 0, stream>>>(flagp, x_fwd, x_bwd, Wk, bias32, xW, 1);
  xw_gemm_k<1><<<dim3(128, 12, 2), 256, 0, stream>>>(flagp, x_fwd, x_bwd, Wk, bias32, xW, 1);

  {
    void* args[] = {&xW, &WrRaw, &flagp, &wpt, &mask32, &out1, &hbuf, &ybuf, &ctrs, &l1};
    hipError_t e = hipLaunchCooperativeKernel((void*)scan_kernel, dim3(512), dim3(256), args, 0, stream);
    if (e != hipSuccess)
      scan_kernel<<<512, 256, 0, stream>>>(xW, WrRaw, flagp, wpt, mask32, out1, hbuf, ybuf, ctrs, 1);
  }

  mixA_k<<<24, 256, 0, stream>>>(emb, out0, out1, mask32, stats);
  mixB_k<<<1536, 256, 0, stream>>>(flagp, emb, out0, out1, stats, ew32, d_out);
}